// Round 3
// baseline (1543.807 us; speedup 1.0000x reference)
//
#include <hip/hip_runtime.h>
#include <hip/hip_bf16.h>

#define NSZ 8192
#define DSZ 128
#define OT_ITERS 20

typedef __bf16 bf16x8 __attribute__((ext_vector_type(8)));
typedef float  f32x4  __attribute__((ext_vector_type(4)));

constexpr float EPS_INV = 20.0f;          // 1 / 0.05
constexpr float MU      = 1.0f / 8192.0f; // = nu

template<typename T> struct vec8t;
template<> struct vec8t<__bf16> { typedef __bf16 type __attribute__((ext_vector_type(8))); };
template<> struct vec8t<float>  { typedef float  type __attribute__((ext_vector_type(8))); };

// ---------------------------------------------------------------------------
// prep: split fp32 rows into bf16 hi/lo, row sum-of-squares, init u = 1
// one wave (64 lanes) per row; waves [0,8192) -> H_m, [8192,16384) -> H_n
// ---------------------------------------------------------------------------
__global__ __launch_bounds__(256)
void prep_kernel(const float* __restrict__ Hm, const float* __restrict__ Hn,
                 __bf16* __restrict__ hiM, __bf16* __restrict__ loM,
                 __bf16* __restrict__ hiN, __bf16* __restrict__ loN,
                 float* __restrict__ sqm, float* __restrict__ sqn,
                 float* __restrict__ u)
{
    int gtid = blockIdx.x * 256 + threadIdx.x;
    int wave = gtid >> 6;
    int lane = threadIdx.x & 63;

    const float* src; __bf16 *hi, *lo; float* sq; int row;
    if (wave < NSZ) { src = Hm; hi = hiM; lo = loM; sq = sqm; row = wave; }
    else            { src = Hn; hi = hiN; lo = loN; sq = sqn; row = wave - NSZ; }

    float s = 0.0f;
    #pragma unroll
    for (int e = 0; e < 2; ++e) {
        int k = lane + 64 * e;
        float x = src[row * DSZ + k];
        s += x * x;
        __bf16 h = (__bf16)x;
        float hf = (float)h;
        __bf16 l = (__bf16)(x - hf);
        hi[row * DSZ + k] = h;
        lo[row * DSZ + k] = l;
    }
    #pragma unroll
    for (int off = 32; off; off >>= 1) s += __shfl_xor(s, off, 64);
    if (lane == 0) sq[row] = s;

    if (gtid < NSZ) u[gtid] = 1.0f;
}

// ---------------------------------------------------------------------------
// gemm<MODE>: cost_ij = max(sq_m[i]+sq_n[j]-2*dot(m_i,n_j), 0); kv = exp(-cost/eps)
//   MODE 0: build K  -> write Kb (bf16, if non-null) and/or Kf (fp32, if non-null)
//   MODE 1: plan     -> write Kf[i][j] = kv * u[i] * v[j]   (fp32, full accuracy)
// split-bf16 MFMA (hi*hi + hi*lo + lo*hi) for ~fp32 dot accuracy.
// block = 256 thr = 4 waves (2x2), tile 128x128, each wave 64x64 (4x4 frags)
// ---------------------------------------------------------------------------
template<int MODE>
__global__ __launch_bounds__(256)
void gemm_kernel(const __bf16* __restrict__ hiM, const __bf16* __restrict__ loM,
                 const __bf16* __restrict__ hiN, const __bf16* __restrict__ loN,
                 const float* __restrict__ sqm, const float* __restrict__ sqn,
                 float* __restrict__ Kf, __bf16* __restrict__ Kb,
                 const float* __restrict__ u, const float* __restrict__ v)
{
    int wid  = threadIdx.x >> 6;
    int lane = threadIdx.x & 63;
    int wr = wid >> 1, wc = wid & 1;
    int ibase = blockIdx.x * 128 + wr * 64;
    int jbase = blockIdx.y * 128 + wc * 64;
    int lrow = lane & 15;
    int koff = (lane >> 4) * 8;   // A/B frag: row/col = lane&15, k = (lane>>4)*8..+8

    f32x4 acc[4][4] = {};

    #pragma unroll
    for (int kk = 0; kk < 4; ++kk) {
        int kpos = kk * 32 + koff;
        bf16x8 ah[4], al[4], bh[4], bl[4];
        #pragma unroll
        for (int m = 0; m < 4; ++m) {
            size_t o = (size_t)(ibase + m * 16 + lrow) * DSZ + kpos;
            ah[m] = *reinterpret_cast<const bf16x8*>(hiM + o);
            al[m] = *reinterpret_cast<const bf16x8*>(loM + o);
        }
        #pragma unroll
        for (int n = 0; n < 4; ++n) {
            size_t o = (size_t)(jbase + n * 16 + lrow) * DSZ + kpos;
            bh[n] = *reinterpret_cast<const bf16x8*>(hiN + o);
            bl[n] = *reinterpret_cast<const bf16x8*>(loN + o);
        }
        #pragma unroll
        for (int m = 0; m < 4; ++m)
        #pragma unroll
        for (int n = 0; n < 4; ++n) {
            acc[m][n] = __builtin_amdgcn_mfma_f32_16x16x32_bf16(ah[m], bh[n], acc[m][n], 0, 0, 0);
            acc[m][n] = __builtin_amdgcn_mfma_f32_16x16x32_bf16(ah[m], bl[n], acc[m][n], 0, 0, 0);
            acc[m][n] = __builtin_amdgcn_mfma_f32_16x16x32_bf16(al[m], bh[n], acc[m][n], 0, 0, 0);
        }
    }

    // C/D layout (m89-verified): col = lane&15, row = (lane>>4)*4 + reg
    int ccol  = lane & 15;
    int crow0 = (lane >> 4) * 4;
    #pragma unroll
    for (int m = 0; m < 4; ++m) {
        int i0 = ibase + m * 16 + crow0;
        float um[4], sm[4];
        #pragma unroll
        for (int r = 0; r < 4; ++r) {
            sm[r] = sqm[i0 + r];
            if (MODE == 1) um[r] = u[i0 + r];
        }
        #pragma unroll
        for (int n = 0; n < 4; ++n) {
            int j = jbase + n * 16 + ccol;
            float sn = sqn[j];
            float vj = (MODE == 1) ? v[j] : 0.0f;
            #pragma unroll
            for (int r = 0; r < 4; ++r) {
                int i = i0 + r;
                float c = sm[r] + sn - 2.0f * acc[m][n][r];
                c = fmaxf(c, 0.0f);
                float kv = __expf(-c * EPS_INV);
                if (MODE == 1) {
                    Kf[(size_t)i * NSZ + j] = kv * um[r] * vj;
                } else {
                    if (Kb) Kb[(size_t)i * NSZ + j] = (__bf16)kv;
                    if (Kf) Kf[(size_t)i * NSZ + j] = kv;
                }
            }
        }
    }
}

// ---------------------------------------------------------------------------
// mv_col: partial[ib][j] = sum_{i in chunk ib} K[i][j] * u[i]
// grid (4, 128): j-tile 2048 wide (256 thr x 8), row chunk = 64
// ---------------------------------------------------------------------------
template<typename KT>
__global__ __launch_bounds__(256)
void mv_col_kernel(const KT* __restrict__ Kmat, const float* __restrict__ u,
                   float* __restrict__ partial)
{
    typedef typename vec8t<KT>::type kvec;
    int j  = blockIdx.x * 2048 + threadIdx.x * 8;
    int ib = blockIdx.y * 64;

    float a[8] = {};
    #pragma unroll 8
    for (int i = 0; i < 64; ++i) {
        int row = ib + i;
        float uv = u[row];
        kvec kv = *reinterpret_cast<const kvec*>(Kmat + (size_t)row * NSZ + j);
        #pragma unroll
        for (int e = 0; e < 8; ++e) a[e] = fmaf((float)kv[e], uv, a[e]);
    }
    float* dst = partial + (size_t)blockIdx.y * NSZ + j;
    f32x4 lo4 = { a[0], a[1], a[2], a[3] };
    f32x4 hi4 = { a[4], a[5], a[6], a[7] };
    *reinterpret_cast<f32x4*>(dst)     = lo4;
    *reinterpret_cast<f32x4*>(dst + 4) = hi4;
}

// ---------------------------------------------------------------------------
// mv_red: t_j = sum_c partial[c][j];  x_j = nu / t_j
// grid 64 x 128 threads (one thread per column j)
// ---------------------------------------------------------------------------
__global__ __launch_bounds__(128)
void mv_red_kernel(const float* __restrict__ partial, float* __restrict__ x)
{
    int j = blockIdx.x * 128 + threadIdx.x;
    float s = 0.0f;
    #pragma unroll 8
    for (int c = 0; c < 128; ++c) s += partial[(size_t)c * NSZ + j];
    x[j] = MU / s;
}

// ---------------------------------------------------------------------------
// mv_row: s_i = sum_j K[i][j] x_j ; u_i = mu / s_i   (fused)
// block 512 (8 waves), grid 512 -> 4096 waves (16/CU); each wave 2 rows in flight
// ---------------------------------------------------------------------------
template<typename KT>
__global__ __launch_bounds__(512)
void mv_row_kernel(const KT* __restrict__ Kmat, const float* __restrict__ x,
                   float* __restrict__ uout)
{
    typedef typename vec8t<KT>::type kvec;
    int lane = threadIdx.x & 63;
    int wave = (blockIdx.x * 512 + threadIdx.x) >> 6;  // 0..4095

    int row0 = wave;
    int row1 = wave + 4096;
    const KT* kr0 = Kmat + (size_t)row0 * NSZ;
    const KT* kr1 = Kmat + (size_t)row1 * NSZ;
    float acc0 = 0.0f, acc1 = 0.0f;
    #pragma unroll 4
    for (int c0 = lane * 8; c0 < NSZ; c0 += 64 * 8) {
        kvec k0 = *reinterpret_cast<const kvec*>(kr0 + c0);
        kvec k1 = *reinterpret_cast<const kvec*>(kr1 + c0);
        f32x4 x0 = *reinterpret_cast<const f32x4*>(x + c0);
        f32x4 x1 = *reinterpret_cast<const f32x4*>(x + c0 + 4);
        acc0 += (float)k0[0]*x0[0] + (float)k0[1]*x0[1] + (float)k0[2]*x0[2] + (float)k0[3]*x0[3]
              + (float)k0[4]*x1[0] + (float)k0[5]*x1[1] + (float)k0[6]*x1[2] + (float)k0[7]*x1[3];
        acc1 += (float)k1[0]*x0[0] + (float)k1[1]*x0[1] + (float)k1[2]*x0[2] + (float)k1[3]*x0[3]
              + (float)k1[4]*x1[0] + (float)k1[5]*x1[1] + (float)k1[6]*x1[2] + (float)k1[7]*x1[3];
    }
    #pragma unroll
    for (int off = 32; off; off >>= 1) {
        acc0 += __shfl_xor(acc0, off, 64);
        acc1 += __shfl_xor(acc1, off, 64);
    }
    if (lane == 0) {
        uout[row0] = MU / acc0;
        uout[row1] = MU / acc1;
    }
}

// ---------------------------------------------------------------------------
// outer: out[i][j] = Kf[i][j] * u[i] * v[j]  in place on d_out  (FALLBACK only)
// ---------------------------------------------------------------------------
__global__ __launch_bounds__(256)
void outer_kernel(float* __restrict__ out, const float* __restrict__ u,
                  const float* __restrict__ v)
{
    size_t t = (size_t)blockIdx.x * 256 + threadIdx.x;   // 16M threads, 4 floats each
    int i  = (int)(t >> 11);
    int j4 = (int)(t & 2047) * 4;
    float* p = out + (size_t)i * NSZ + j4;
    f32x4 k4 = *reinterpret_cast<f32x4*>(p);
    f32x4 v4 = *reinterpret_cast<const f32x4*>(v + j4);
    float s = u[i];
    k4[0] = k4[0] * s * v4[0];
    k4[1] = k4[1] * s * v4[1];
    k4[2] = k4[2] * s * v4[2];
    k4[3] = k4[3] * s * v4[3];
    *reinterpret_cast<f32x4*>(p) = k4;
}

// ---------------------------------------------------------------------------
extern "C" void kernel_launch(void* const* d_in, const int* in_sizes, int n_in,
                              void* d_out, int out_size, void* d_ws, size_t ws_size,
                              hipStream_t stream)
{
    const float* Hm = (const float*)d_in[0];
    const float* Hn = (const float*)d_in[1];
    float* out = (float*)d_out;

    char* ws = (char*)d_ws;
    size_t off = 0;
    auto alloc = [&](size_t bytes) -> void* {
        void* p = ws + off;
        off += (bytes + 255) & ~(size_t)255;
        return p;
    };

    __bf16* hiM = (__bf16*)alloc((size_t)NSZ * DSZ * 2);
    __bf16* loM = (__bf16*)alloc((size_t)NSZ * DSZ * 2);
    __bf16* hiN = (__bf16*)alloc((size_t)NSZ * DSZ * 2);
    __bf16* loN = (__bf16*)alloc((size_t)NSZ * DSZ * 2);
    float*  sqm = (float*)alloc(NSZ * 4);
    float*  sqn = (float*)alloc(NSZ * 4);
    float*  u   = (float*)alloc(NSZ * 4);
    float*  x   = (float*)alloc(NSZ * 4);
    float*  v   = (float*)alloc(NSZ * 4);
    float*  partial = (float*)alloc((size_t)128 * NSZ * 4);
    __bf16* Kb = (__bf16*)alloc((size_t)NSZ * NSZ * 2);
    bool use_bf16 = (ws_size >= off);
    (void)in_sizes; (void)n_in; (void)out_size;

    // 1) prep: bf16 hi/lo split + row norms + u = 1
    prep_kernel<<<dim3(2 * NSZ / 4), dim3(256), 0, stream>>>(Hm, Hn, hiM, loM, hiN, loN, sqm, sqn, u);

    // 2) build K.
    //    primary: bf16 K only (128 MB write) -> plan is recomputed in step 5.
    //    fallback (ws too small): fp32 K into d_out, finish with in-place outer.
    if (use_bf16) {
        gemm_kernel<0><<<dim3(64, 64), dim3(256), 0, stream>>>(
            hiM, loM, hiN, loN, sqm, sqn, nullptr, Kb, nullptr, nullptr);
    } else {
        gemm_kernel<0><<<dim3(64, 64), dim3(256), 0, stream>>>(
            hiM, loM, hiN, loN, sqm, sqn, out, nullptr, nullptr, nullptr);
    }

    // 3) Sinkhorn: u_{t+1} = mu / (K (nu / (K^T u_t))), 20 iterations
    for (int it = 0; it < OT_ITERS; ++it) {
        if (use_bf16) {
            mv_col_kernel<__bf16><<<dim3(4, 128), dim3(256), 0, stream>>>(Kb, u, partial);
            mv_red_kernel<<<dim3(64), dim3(128), 0, stream>>>(partial, x);
            mv_row_kernel<__bf16><<<dim3(512), dim3(512), 0, stream>>>(Kb, x, u);
        } else {
            mv_col_kernel<float><<<dim3(4, 128), dim3(256), 0, stream>>>(out, u, partial);
            mv_red_kernel<<<dim3(64), dim3(128), 0, stream>>>(partial, x);
            mv_row_kernel<float><<<dim3(512), dim3(512), 0, stream>>>(out, x, u);
        }
    }

    // 4) v = nu / (K^T u)
    if (use_bf16) {
        mv_col_kernel<__bf16><<<dim3(4, 128), dim3(256), 0, stream>>>(Kb, u, partial);
    } else {
        mv_col_kernel<float><<<dim3(4, 128), dim3(256), 0, stream>>>(out, u, partial);
    }
    mv_red_kernel<<<dim3(64), dim3(128), 0, stream>>>(partial, v);

    // 5) plan
    if (use_bf16) {
        // recompute cost->exp in fp32 fused with u_i * v_j, single 256 MB write
        gemm_kernel<1><<<dim3(64, 64), dim3(256), 0, stream>>>(
            hiM, loM, hiN, loN, sqm, sqn, out, nullptr, u, v);
    } else {
        outer_kernel<<<dim3((unsigned)((size_t)NSZ * NSZ / 4 / 256)), dim3(256), 0, stream>>>(out, u, v);
    }
}

// Round 4
// 1153.703 us; speedup vs baseline: 1.3381x; 1.3381x over previous
//
#include <hip/hip_runtime.h>
#include <hip/hip_bf16.h>

#define NSZ 8192
#define DSZ 128
#define OT_ITERS 20

typedef __bf16 bf16x8 __attribute__((ext_vector_type(8)));
typedef float  f32x4  __attribute__((ext_vector_type(4)));
typedef float  f32x2  __attribute__((ext_vector_type(2)));
typedef unsigned int u32x2 __attribute__((ext_vector_type(2)));

constexpr float EPS_INV  = 20.0f;          // 1 / 0.05
constexpr float MU       = 1.0f / 8192.0f; // = nu
constexpr float K8_SCALE = 64.0f;          // fp8 K stored as 64*K (all values e4m3-normal)

// ---------------------------------------------------------------------------
// prep: split fp32 rows into bf16 hi/lo, row sum-of-squares, init u = 1
// one wave (64 lanes) per row; waves [0,8192) -> H_m, [8192,16384) -> H_n
// ---------------------------------------------------------------------------
__global__ __launch_bounds__(256)
void prep_kernel(const float* __restrict__ Hm, const float* __restrict__ Hn,
                 __bf16* __restrict__ hiM, __bf16* __restrict__ loM,
                 __bf16* __restrict__ hiN, __bf16* __restrict__ loN,
                 float* __restrict__ sqm, float* __restrict__ sqn,
                 float* __restrict__ u)
{
    int gtid = blockIdx.x * 256 + threadIdx.x;
    int wave = gtid >> 6;
    int lane = threadIdx.x & 63;

    const float* src; __bf16 *hi, *lo; float* sq; int row;
    if (wave < NSZ) { src = Hm; hi = hiM; lo = loM; sq = sqm; row = wave; }
    else            { src = Hn; hi = hiN; lo = loN; sq = sqn; row = wave - NSZ; }

    float s = 0.0f;
    #pragma unroll
    for (int e = 0; e < 2; ++e) {
        int k = lane + 64 * e;
        float x = src[row * DSZ + k];
        s += x * x;
        __bf16 h = (__bf16)x;
        float hf = (float)h;
        __bf16 l = (__bf16)(x - hf);
        hi[row * DSZ + k] = h;
        lo[row * DSZ + k] = l;
    }
    #pragma unroll
    for (int off = 32; off; off >>= 1) s += __shfl_xor(s, off, 64);
    if (lane == 0) sq[row] = s;

    if (gtid < NSZ) u[gtid] = 1.0f;
}

// ---------------------------------------------------------------------------
// gemm<MODE>: cost_ij = max(sq_m[i]+sq_n[j]-2*dot(m_i,n_j), 0); kv = exp(-cost/eps)
//   MODE 0: build K  -> K8 (fp8 e4m3, value 64*kv) or Kf (fp32 fallback)
//   MODE 1: plan     -> Kf[i][j] = kv * u[i] * (64*v[j])   (fp32, full accuracy;
//                       64 compensates the fp8 K scale carried by v)
// split-bf16 MFMA (hi*hi + hi*lo + lo*hi) for ~fp32 dot accuracy.
// OPERAND-SWAPPED: mfma(N-frag, M-frag) => per-lane acc regs walk j
//   lane holds: i = base + (lane&15),  j = base + (lane>>4)*4 + reg  (4 consec j)
// => f32x4 / packed-fp8-dword stores instead of 64 scalar stores.
// block = 256 thr = 4 waves (2x2), tile 128x128, each wave 64x64 (4x4 frags)
// ---------------------------------------------------------------------------
template<int MODE>
__global__ __launch_bounds__(256)
void gemm_kernel(const __bf16* __restrict__ hiM, const __bf16* __restrict__ loM,
                 const __bf16* __restrict__ hiN, const __bf16* __restrict__ loN,
                 const float* __restrict__ sqm, const float* __restrict__ sqn,
                 float* __restrict__ Kf, unsigned char* __restrict__ K8,
                 const float* __restrict__ u, const float* __restrict__ v)
{
    int wid  = threadIdx.x >> 6;
    int lane = threadIdx.x & 63;
    int wr = wid >> 1, wc = wid & 1;
    int ibase = blockIdx.x * 128 + wr * 64;
    int jbase = blockIdx.y * 128 + wc * 64;
    int lrow = lane & 15;
    int koff = (lane >> 4) * 8;   // A/B frag: row/col = lane&15, k = (lane>>4)*8..+8

    f32x4 acc[4][4] = {};

    #pragma unroll
    for (int kk = 0; kk < 4; ++kk) {
        int kpos = kk * 32 + koff;
        bf16x8 ah[4], al[4], bh[4], bl[4];
        #pragma unroll
        for (int m = 0; m < 4; ++m) {
            size_t o = (size_t)(ibase + m * 16 + lrow) * DSZ + kpos;
            ah[m] = *reinterpret_cast<const bf16x8*>(hiM + o);
            al[m] = *reinterpret_cast<const bf16x8*>(loM + o);
        }
        #pragma unroll
        for (int n = 0; n < 4; ++n) {
            size_t o = (size_t)(jbase + n * 16 + lrow) * DSZ + kpos;
            bh[n] = *reinterpret_cast<const bf16x8*>(hiN + o);
            bl[n] = *reinterpret_cast<const bf16x8*>(loN + o);
        }
        // swapped: first operand = N rows (-> output reg dim = j)
        #pragma unroll
        for (int m = 0; m < 4; ++m)
        #pragma unroll
        for (int n = 0; n < 4; ++n) {
            acc[m][n] = __builtin_amdgcn_mfma_f32_16x16x32_bf16(bh[n], ah[m], acc[m][n], 0, 0, 0);
            acc[m][n] = __builtin_amdgcn_mfma_f32_16x16x32_bf16(bl[n], ah[m], acc[m][n], 0, 0, 0);
            acc[m][n] = __builtin_amdgcn_mfma_f32_16x16x32_bf16(bh[n], al[m], acc[m][n], 0, 0, 0);
        }
    }

    int il  = lane & 15;          // i-local
    int jl0 = (lane >> 4) * 4;    // j-local base (regs walk j)
    #pragma unroll
    for (int m = 0; m < 4; ++m) {
        int i = ibase + m * 16 + il;
        float sm = sqm[i];
        float um = (MODE == 1) ? u[i] : 0.0f;
        #pragma unroll
        for (int n = 0; n < 4; ++n) {
            int j0 = jbase + n * 16 + jl0;
            f32x4 sn4 = *reinterpret_cast<const f32x4*>(sqn + j0);
            f32x4 kv4;
            #pragma unroll
            for (int r = 0; r < 4; ++r) {
                float c = sm + sn4[r] - 2.0f * acc[m][n][r];
                c = fmaxf(c, 0.0f);
                kv4[r] = __expf(-c * EPS_INV);
            }
            if (MODE == 1) {
                f32x4 v4 = *reinterpret_cast<const f32x4*>(v + j0);
                f32x4 o4;
                #pragma unroll
                for (int r = 0; r < 4; ++r) o4[r] = kv4[r] * um * (K8_SCALE * v4[r]);
                *reinterpret_cast<f32x4*>(Kf + (size_t)i * NSZ + j0) = o4;
            } else {
                if (K8) {
                    int w = __builtin_amdgcn_cvt_pk_fp8_f32(kv4[0] * K8_SCALE, kv4[1] * K8_SCALE, 0, false);
                    w     = __builtin_amdgcn_cvt_pk_fp8_f32(kv4[2] * K8_SCALE, kv4[3] * K8_SCALE, w, true);
                    *reinterpret_cast<unsigned int*>(K8 + (size_t)i * NSZ + j0) = (unsigned int)w;
                } else {
                    *reinterpret_cast<f32x4*>(Kf + (size_t)i * NSZ + j0) = kv4;
                }
            }
        }
    }
}

// ---------------------------------------------------------------------------
// mv_col8: partial[ib][j] = sum_{i in chunk ib} 64K[i][j] * u[i]   (fp8 K)
// grid (4, 128): j-tile 2048 wide (256 thr x 8), row chunk = 64
// ---------------------------------------------------------------------------
__global__ __launch_bounds__(256)
void mv_col8_kernel(const unsigned char* __restrict__ K8, const float* __restrict__ u,
                    float* __restrict__ partial)
{
    int j  = blockIdx.x * 2048 + threadIdx.x * 8;
    int ib = blockIdx.y * 64;

    float a[8] = {};
    #pragma unroll 8
    for (int i = 0; i < 64; ++i) {
        int row = ib + i;
        float uv = u[row];
        u32x2 w = *reinterpret_cast<const u32x2*>(K8 + (size_t)row * NSZ + j);
        f32x2 p;
        p = __builtin_amdgcn_cvt_pk_f32_fp8((int)w[0], false);
        a[0] = fmaf(p.x, uv, a[0]); a[1] = fmaf(p.y, uv, a[1]);
        p = __builtin_amdgcn_cvt_pk_f32_fp8((int)w[0], true);
        a[2] = fmaf(p.x, uv, a[2]); a[3] = fmaf(p.y, uv, a[3]);
        p = __builtin_amdgcn_cvt_pk_f32_fp8((int)w[1], false);
        a[4] = fmaf(p.x, uv, a[4]); a[5] = fmaf(p.y, uv, a[5]);
        p = __builtin_amdgcn_cvt_pk_f32_fp8((int)w[1], true);
        a[6] = fmaf(p.x, uv, a[6]); a[7] = fmaf(p.y, uv, a[7]);
    }
    float* dst = partial + (size_t)blockIdx.y * NSZ + j;
    f32x4 lo4 = { a[0], a[1], a[2], a[3] };
    f32x4 hi4 = { a[4], a[5], a[6], a[7] };
    *reinterpret_cast<f32x4*>(dst)     = lo4;
    *reinterpret_cast<f32x4*>(dst + 4) = hi4;
}

// ---------------------------------------------------------------------------
// mv_red: t_j = sum_c partial[c][j];  x_j = nu / t_j
// ---------------------------------------------------------------------------
__global__ __launch_bounds__(128)
void mv_red_kernel(const float* __restrict__ partial, float* __restrict__ x)
{
    int j = blockIdx.x * 128 + threadIdx.x;
    float s = 0.0f;
    #pragma unroll 8
    for (int c = 0; c < 128; ++c) s += partial[(size_t)c * NSZ + j];
    x[j] = MU / s;
}

// ---------------------------------------------------------------------------
// mv_row8: s_i = sum_j 64K[i][j] x_j ; u_i = mu / s_i   (fp8 K, fused)
// block 512 (8 waves), grid 512 -> 4096 waves; each wave 2 rows in flight
// ---------------------------------------------------------------------------
__global__ __launch_bounds__(512)
void mv_row8_kernel(const unsigned char* __restrict__ K8, const float* __restrict__ x,
                    float* __restrict__ uout)
{
    int lane = threadIdx.x & 63;
    int wave = (blockIdx.x * 512 + threadIdx.x) >> 6;  // 0..4095

    int row0 = wave;
    int row1 = wave + 4096;
    const unsigned char* kr0 = K8 + (size_t)row0 * NSZ;
    const unsigned char* kr1 = K8 + (size_t)row1 * NSZ;
    float acc0 = 0.0f, acc1 = 0.0f;
    #pragma unroll 4
    for (int c0 = lane * 8; c0 < NSZ; c0 += 64 * 8) {
        u32x2 w0 = *reinterpret_cast<const u32x2*>(kr0 + c0);
        u32x2 w1 = *reinterpret_cast<const u32x2*>(kr1 + c0);
        f32x4 xa = *reinterpret_cast<const f32x4*>(x + c0);
        f32x4 xb = *reinterpret_cast<const f32x4*>(x + c0 + 4);
        f32x2 p;
        p = __builtin_amdgcn_cvt_pk_f32_fp8((int)w0[0], false);
        acc0 = fmaf(p.x, xa[0], fmaf(p.y, xa[1], acc0));
        p = __builtin_amdgcn_cvt_pk_f32_fp8((int)w0[0], true);
        acc0 = fmaf(p.x, xa[2], fmaf(p.y, xa[3], acc0));
        p = __builtin_amdgcn_cvt_pk_f32_fp8((int)w0[1], false);
        acc0 = fmaf(p.x, xb[0], fmaf(p.y, xb[1], acc0));
        p = __builtin_amdgcn_cvt_pk_f32_fp8((int)w0[1], true);
        acc0 = fmaf(p.x, xb[2], fmaf(p.y, xb[3], acc0));
        p = __builtin_amdgcn_cvt_pk_f32_fp8((int)w1[0], false);
        acc1 = fmaf(p.x, xa[0], fmaf(p.y, xa[1], acc1));
        p = __builtin_amdgcn_cvt_pk_f32_fp8((int)w1[0], true);
        acc1 = fmaf(p.x, xa[2], fmaf(p.y, xa[3], acc1));
        p = __builtin_amdgcn_cvt_pk_f32_fp8((int)w1[1], false);
        acc1 = fmaf(p.x, xb[0], fmaf(p.y, xb[1], acc1));
        p = __builtin_amdgcn_cvt_pk_f32_fp8((int)w1[1], true);
        acc1 = fmaf(p.x, xb[2], fmaf(p.y, xb[3], acc1));
    }
    #pragma unroll
    for (int off = 32; off; off >>= 1) {
        acc0 += __shfl_xor(acc0, off, 64);
        acc1 += __shfl_xor(acc1, off, 64);
    }
    if (lane == 0) {
        uout[row0] = MU / acc0;
        uout[row1] = MU / acc1;
    }
}

// ---------------------------------------------------------------------------
// fp32 fallback matvecs (only used if ws is too small for fp8 K)
// ---------------------------------------------------------------------------
__global__ __launch_bounds__(256)
void mv_colf_kernel(const float* __restrict__ Kmat, const float* __restrict__ u,
                    float* __restrict__ partial)
{
    typedef float f32x8 __attribute__((ext_vector_type(8)));
    int j  = blockIdx.x * 2048 + threadIdx.x * 8;
    int ib = blockIdx.y * 64;
    float a[8] = {};
    #pragma unroll 8
    for (int i = 0; i < 64; ++i) {
        int row = ib + i;
        float uv = u[row];
        f32x8 kv = *reinterpret_cast<const f32x8*>(Kmat + (size_t)row * NSZ + j);
        #pragma unroll
        for (int e = 0; e < 8; ++e) a[e] = fmaf(kv[e], uv, a[e]);
    }
    float* dst = partial + (size_t)blockIdx.y * NSZ + j;
    f32x4 lo4 = { a[0], a[1], a[2], a[3] };
    f32x4 hi4 = { a[4], a[5], a[6], a[7] };
    *reinterpret_cast<f32x4*>(dst)     = lo4;
    *reinterpret_cast<f32x4*>(dst + 4) = hi4;
}

__global__ __launch_bounds__(512)
void mv_rowf_kernel(const float* __restrict__ Kmat, const float* __restrict__ x,
                    float* __restrict__ uout)
{
    typedef float f32x8 __attribute__((ext_vector_type(8)));
    int lane = threadIdx.x & 63;
    int wave = (blockIdx.x * 512 + threadIdx.x) >> 6;
    int row0 = wave, row1 = wave + 4096;
    const float* kr0 = Kmat + (size_t)row0 * NSZ;
    const float* kr1 = Kmat + (size_t)row1 * NSZ;
    float acc0 = 0.0f, acc1 = 0.0f;
    #pragma unroll 4
    for (int c0 = lane * 8; c0 < NSZ; c0 += 64 * 8) {
        f32x8 k0 = *reinterpret_cast<const f32x8*>(kr0 + c0);
        f32x8 k1 = *reinterpret_cast<const f32x8*>(kr1 + c0);
        #pragma unroll
        for (int e = 0; e < 8; ++e) {
            float xv = x[c0 + e];
            acc0 = fmaf(k0[e], xv, acc0);
            acc1 = fmaf(k1[e], xv, acc1);
        }
    }
    #pragma unroll
    for (int off = 32; off; off >>= 1) {
        acc0 += __shfl_xor(acc0, off, 64);
        acc1 += __shfl_xor(acc1, off, 64);
    }
    if (lane == 0) { uout[row0] = MU / acc0; uout[row1] = MU / acc1; }
}

// ---------------------------------------------------------------------------
// outer: out[i][j] = Kf[i][j] * u[i] * v[j]  in place on d_out  (FALLBACK only)
// ---------------------------------------------------------------------------
__global__ __launch_bounds__(256)
void outer_kernel(float* __restrict__ out, const float* __restrict__ u,
                  const float* __restrict__ v)
{
    size_t t = (size_t)blockIdx.x * 256 + threadIdx.x;
    int i  = (int)(t >> 11);
    int j4 = (int)(t & 2047) * 4;
    float* p = out + (size_t)i * NSZ + j4;
    f32x4 k4 = *reinterpret_cast<f32x4*>(p);
    f32x4 v4 = *reinterpret_cast<const f32x4*>(v + j4);
    float s = u[i];
    k4[0] = k4[0] * s * v4[0];
    k4[1] = k4[1] * s * v4[1];
    k4[2] = k4[2] * s * v4[2];
    k4[3] = k4[3] * s * v4[3];
    *reinterpret_cast<f32x4*>(p) = k4;
}

// ---------------------------------------------------------------------------
extern "C" void kernel_launch(void* const* d_in, const int* in_sizes, int n_in,
                              void* d_out, int out_size, void* d_ws, size_t ws_size,
                              hipStream_t stream)
{
    const float* Hm = (const float*)d_in[0];
    const float* Hn = (const float*)d_in[1];
    float* out = (float*)d_out;

    char* ws = (char*)d_ws;
    size_t off = 0;
    auto alloc = [&](size_t bytes) -> void* {
        void* p = ws + off;
        off += (bytes + 255) & ~(size_t)255;
        return p;
    };

    __bf16* hiM = (__bf16*)alloc((size_t)NSZ * DSZ * 2);
    __bf16* loM = (__bf16*)alloc((size_t)NSZ * DSZ * 2);
    __bf16* hiN = (__bf16*)alloc((size_t)NSZ * DSZ * 2);
    __bf16* loN = (__bf16*)alloc((size_t)NSZ * DSZ * 2);
    float*  sqm = (float*)alloc(NSZ * 4);
    float*  sqn = (float*)alloc(NSZ * 4);
    float*  u   = (float*)alloc(NSZ * 4);
    float*  x   = (float*)alloc(NSZ * 4);
    float*  v   = (float*)alloc(NSZ * 4);
    float*  partial = (float*)alloc((size_t)128 * NSZ * 4);
    unsigned char* K8 = (unsigned char*)alloc((size_t)NSZ * NSZ);  // 64 MiB fp8 K
    bool use_fp8 = (ws_size >= off);
    (void)in_sizes; (void)n_in; (void)out_size;

    // 1) prep: bf16 hi/lo split + row norms + u = 1
    prep_kernel<<<dim3(2 * NSZ / 4), dim3(256), 0, stream>>>(Hm, Hn, hiM, loM, hiN, loN, sqm, sqn, u);

    // 2) build K (fp8 scaled by 64; fp32 into d_out if ws too small)
    if (use_fp8) {
        gemm_kernel<0><<<dim3(64, 64), dim3(256), 0, stream>>>(
            hiM, loM, hiN, loN, sqm, sqn, nullptr, K8, nullptr, nullptr);
    } else {
        gemm_kernel<0><<<dim3(64, 64), dim3(256), 0, stream>>>(
            hiM, loM, hiN, loN, sqm, sqn, out, nullptr, nullptr, nullptr);
    }

    // 3) Sinkhorn: u_{t+1} = mu / (K (nu / (K^T u_t))), 20 iterations
    //    NOTE: the 64x K-scale cancels exactly within each composite iteration
    //    (u iterates are scale-free); only v below carries a 1/64.
    for (int it = 0; it < OT_ITERS; ++it) {
        if (use_fp8) {
            mv_col8_kernel<<<dim3(4, 128), dim3(256), 0, stream>>>(K8, u, partial);
            mv_red_kernel<<<dim3(64), dim3(128), 0, stream>>>(partial, x);
            mv_row8_kernel<<<dim3(512), dim3(512), 0, stream>>>(K8, x, u);
        } else {
            mv_colf_kernel<<<dim3(4, 128), dim3(256), 0, stream>>>(out, u, partial);
            mv_red_kernel<<<dim3(64), dim3(128), 0, stream>>>(partial, x);
            mv_rowf_kernel<<<dim3(512), dim3(512), 0, stream>>>(out, x, u);
        }
    }

    // 4) v = nu / (K^T u)   (carries 1/64 in fp8 path, compensated in gemm<1>)
    if (use_fp8) {
        mv_col8_kernel<<<dim3(4, 128), dim3(256), 0, stream>>>(K8, u, partial);
    } else {
        mv_colf_kernel<<<dim3(4, 128), dim3(256), 0, stream>>>(out, u, partial);
    }
    mv_red_kernel<<<dim3(64), dim3(128), 0, stream>>>(partial, v);

    // 5) plan
    if (use_fp8) {
        gemm_kernel<1><<<dim3(64, 64), dim3(256), 0, stream>>>(
            hiM, loM, hiN, loN, sqm, sqn, out, nullptr, u, v);
    } else {
        outer_kernel<<<dim3((unsigned)((size_t)NSZ * NSZ / 4 / 256)), dim3(256), 0, stream>>>(out, u, v);
    }
}